// Round 7
// baseline (208.377 us; speedup 1.0000x reference)
//
#include <hip/hip_runtime.h>
#include <hip/hip_cooperative_groups.h>

namespace cg = cooperative_groups;

// SetConv RBF: B=4, NQ=4096, NC=4096, DC=2, DY=8, fp32.
// out[b,q,0:8] = sum_c w(q,c)*y[c] / (den+1e-8); out[b,q,8] = den = sum_c w(q,c)
//
// MEASURED LAWS (prior session R1-R10, this session R11-R16):
//  - dur_us = ~41us harness d_ws poison fill + ~10us fixed + kernel time.
//  - Dense MFMA path: accum ~20us + reduce ~2.5us => 73.6 total (67M pairs).
//  - Binning FALSIFIED (R11-R13, best 118us): pipeline tax + latency-bound
//    sparse loops >= pair savings at this size.
//  - ACCUM: invariant to DS count (R14), occupancy 4->6 w/SIMD (R15).
//  - R16 CALIBRATION: +32 VALU cyc/jp => +7.3us measured vs +6.8 predicted
//    => VALU marginal slope = 1 (pipe saturated at margin). v_exp_f32 is
//    ~full-rate (TRANS exonerated). v_pk ops cost 2x cycles on SIMD-32 =>
//    pk packing never cut cycles (explains R10 null). exp2(a0) per-query
//    factoring overflows bf16 => dead. Source-level VALU diet exhausted.
// R17: attack launch overhead. Fuse accum+reduce into ONE cooperative kernel
// (grid=1024=4/CU exact, cg::grid.sync between phases; phase2 spread over all
// 1024 blocks, 16 q each). Fallback to proven 2-kernel path if coop launch
// errors. ws reads in phase2 via agent-scope atomic loads (XCD safety).
// Predicted: dur 67-71 if gaps ~3-8us; ~73.6 if coop fell back / gaps tiny.

#define BB 4
#define NQ 4096
#define NC 4096
#define DY 8
#define NBQ (BB * NQ)           // 16384 queries total

#if __has_builtin(__builtin_amdgcn_exp2f)
#define EXP2F(x) __builtin_amdgcn_exp2f(x)
#else
#define EXP2F(x) exp2f(x)
#endif

typedef short bf16x8 __attribute__((ext_vector_type(8)));
typedef float f32x4  __attribute__((ext_vector_type(4)));
typedef float f32x2  __attribute__((ext_vector_type(2)));

__device__ __forceinline__ short f2bf(float v) {
    return (short)(__builtin_bit_cast(unsigned, v) >> 16);   // truncate
}
__device__ __forceinline__ unsigned fbits(float v) {
    return __builtin_bit_cast(unsigned, v);
}
// pack hi16(w0) -> low half, hi16(w1) -> high half (bf16 pair dword)
__device__ __forceinline__ unsigned bfpair(float w0, float w1) {
#if __has_builtin(__builtin_amdgcn_perm)
    return __builtin_amdgcn_perm(fbits(w1), fbits(w0), 0x07060302u);
#else
    return (fbits(w1) & 0xFFFF0000u) | (fbits(w0) >> 16);
#endif
}

// ---------------- geometry (R14-proven) ----------------
#define GSPLIT 8                     // global context split
#define CCHUNK (NC / GSPLIT)         // 512 contexts per block
#define NPAIR (CCHUNK / 2)           // 256 context pairs
#define KSTEPS (CCHUNK / 32)         // 16 mfma k-steps
#define QPB 128                      // queries per block: 8 tiles x 16
#define NT 8                         // q-tiles per block
#define KPW (KSTEPS / 4)             // 4 k-steps per wave
#define QB (NBQ / QPB)               // 128 query-blocks
#define NBLK (QB * GSPLIT)           // 1024 blocks = 4/CU exactly
#define JS ((size_t)GSPLIT * NBQ)                     // 131072
#define WS_FLOATS ((size_t)(DY + 1) * GSPLIT * NBQ)   // 1.18M floats = 4.7 MB

// ---- accum phase body (shared by fused + standalone kernels) ----
__device__ __forceinline__ void accum_phase(
    const float* __restrict__ xq, const float* __restrict__ xc,
    const float* __restrict__ yc, const float* __restrict__ lls,
    float* __restrict__ ws,
    float4* sxp, float2* shp, unsigned short (*yfrag)[16][8])
{
    const int bid  = blockIdx.x;              // 0..1023
    const int gs   = bid & (GSPLIT - 1);
    const int qb   = bid >> 3;                // 0..127
    const int b    = qb >> 5;                 // 32 q-blocks per batch
    const int tid  = threadIdx.x;
    const int lane = tid & 63;
    const int wv   = tid >> 6;
    const int m    = lane & 15;               // A row / D col index
    const int quad = lane >> 4;

    const float L    = lls[0];
    const float negk = -0.72134752044448f * EXP2F(L * -2.8853900817779268f);

    // ---- stage ctx pairs: tid == pair index (proven) ----
    {
        const float4* xcp = (const float4*)(((const float2*)xc) + (size_t)b * NC + gs * CCHUNK);
        const float4 v = xcp[tid];            // (cx0,cy0,cx1,cy1)
        sxp[tid] = make_float4(v.x, v.z, v.y, v.w);
        shp[tid] = make_float2(negk * fmaf(v.x, v.x, v.y * v.y),
                               negk * fmaf(v.z, v.z, v.w * v.w));
    }
    // ---- stage Ytilde in B-fragment layout: yfrag[g][n][j] = Y[8g+j][n] ----
    {
        const float4* yp = (const float4*)(yc + ((size_t)b * NC + gs * CCHUNK) * DY);
#pragma unroll
        for (int i = 0; i < 2; ++i) {
            const int c = tid + 256 * i;
            const float4 A  = yp[2 * c + 0];
            const float4 Bv = yp[2 * c + 1];
            const int g = c >> 3, j = c & 7;
            unsigned short* dst = &yfrag[g][0][j];
            dst[0 * 8] = (unsigned short)f2bf(A.x);
            dst[1 * 8] = (unsigned short)f2bf(A.y);
            dst[2 * 8] = (unsigned short)f2bf(A.z);
            dst[3 * 8] = (unsigned short)f2bf(A.w);
            dst[4 * 8] = (unsigned short)f2bf(Bv.x);
            dst[5 * 8] = (unsigned short)f2bf(Bv.y);
            dst[6 * 8] = (unsigned short)f2bf(Bv.z);
            dst[7 * 8] = (unsigned short)f2bf(Bv.w);
        }
        // cols 8..15: col 8 = 1.0 (density), 9..15 = 0
        unsigned* yf32 = (unsigned*)yfrag;    // u32 idx = g*64 + n*4 + (j>>1)
#pragma unroll
        for (int i = 0; i < 8; ++i) {         // (CCHUNK/8)*32/256 = 8
            const int v = tid + 256 * i;
            const int g = v >> 5, r = v & 31; // r = (n-8)*4 + jpair
            yf32[g * 64 + 32 + r] = (r < 4) ? 0x3F803F80u : 0u;
        }
    }

    // ---- per-query coefficients for ALL 8 tiles (lane m = query row) ----
    float A0s[NT], A1s[NT], A2s[NT];
#pragma unroll
    for (int t = 0; t < NT; ++t) {
        const int q = qb * QPB + t * 16 + m;
        const float2 qv = ((const float2*)xq)[q];
        A0s[t] = negk * fmaf(qv.x, qv.x, qv.y * qv.y);
        A1s[t] = -2.f * negk * qv.x;
        A2s[t] = -2.f * negk * qv.y;
    }

    f32x4 acc[NT];
#pragma unroll
    for (int t = 0; t < NT; ++t) acc[t] = (f32x4){0.f, 0.f, 0.f, 0.f};

    __syncthreads();

    // ---- hot loop: wave wv owns k-steps 4wv..4wv+3, ALL 8 q-tiles (R14) ----
    for (int ks = 0; ks < KPW; ++ks) {
        const int s = wv * KPW + ks;
        const bf16x8 bfrag = *(const bf16x8*)&yfrag[s * 4 + quad][m][0];
        float4 xp[4]; float2 hp[4];
#pragma unroll
        for (int jp = 0; jp < 4; ++jp) {
            const int P = s * 16 + quad * 4 + jp;
            xp[jp] = sxp[P];
            hp[jp] = shp[P];
        }
#pragma unroll
        for (int t = 0; t < NT; ++t) {
            const f32x2 a0 = {A0s[t], A0s[t]};
            const f32x2 a1 = {A1s[t], A1s[t]};
            const f32x2 a2 = {A2s[t], A2s[t]};
            unsigned au[4];
#pragma unroll
            for (int jp = 0; jp < 4; ++jp) {
                const f32x2 cx2 = {xp[jp].x, xp[jp].y};
                const f32x2 cy2 = {xp[jp].z, xp[jp].w};
                const f32x2 hc2 = {hp[jp].x, hp[jp].y};
                f32x2 tt = __builtin_elementwise_fma(cx2, a1, hc2 + a0);
                tt = __builtin_elementwise_fma(cy2, a2, tt);
                au[jp] = bfpair(EXP2F(tt.x), EXP2F(tt.y));
            }
            const bf16x8 af = __builtin_bit_cast(bf16x8, *(uint4*)au);
            acc[t] = __builtin_amdgcn_mfma_f32_16x16x32_bf16(af, bfrag, acc[t], 0, 0, 0);
        }
    }

    // ---- cross-wave reduce of k-split partials, write ws (R14-proven) ----
    __syncthreads();                          // all yfrag/sxp reads done
    float4* rb = (float4*)&yfrag[0][0][0];    // 2*4*64 float4 = 8 KB reuse
    for (int h = 0; h < 4; ++h) {             // 2 tiles per round
#pragma unroll
        for (int u = 0; u < 2; ++u) {
            const int t = h * 2 + u;
            rb[(u * 4 + wv) * 64 + lane] =
                make_float4(acc[t][0], acc[t][1], acc[t][2], acc[t][3]);
        }
        __syncthreads();
        if (wv == h && m <= 8) {
#pragma unroll
            for (int u = 0; u < 2; ++u) {
                const int t = h * 2 + u;
                float4 v = rb[(u * 4 + 0) * 64 + lane];
#pragma unroll
                for (int w = 1; w < 4; ++w) {
                    const float4 z = rb[(u * 4 + w) * 64 + lane];
                    v.x += z.x; v.y += z.y; v.z += z.z; v.w += z.w;
                }
                *(float4*)&ws[(size_t)m * JS + (size_t)gs * NBQ +
                              (size_t)qb * QPB + t * 16 + quad * 4] = v;
            }
        }
        __syncthreads();
    }
}

// ---- fused cooperative kernel: accum -> grid.sync -> reduce+normalize ----
__global__ __launch_bounds__(256, 4) void setconv_fused(
    const float* __restrict__ xq, const float* __restrict__ xc,
    const float* __restrict__ yc, const float* __restrict__ lls,
    float* __restrict__ ws, float* __restrict__ out)
{
    __shared__ float4 sxp[NPAIR];
    __shared__ float2 shp[NPAIR];
    __shared__ __attribute__((aligned(16)))
        unsigned short yfrag[CCHUNK / 8][16][8];

    accum_phase(xq, xc, yc, lls, ws, sxp, shp, yfrag);

    __threadfence();                 // release ws writes (belt & suspenders)
    cg::this_grid().sync();          // all 1024 blocks co-resident (4/CU)

    // phase 2: each block reduces 16 queries (1024 x 16 = 16384).
    const int tid = threadIdx.x;
    if (tid < 16 * (DY + 1)) {
        const int q2 = tid / (DY + 1);
        const int j  = tid - q2 * (DY + 1);
        const int bq = blockIdx.x * 16 + q2;
        float s = 0.f, den = 0.f;
#pragma unroll
        for (int k = 0; k < GSPLIT; ++k) {
            s   += __hip_atomic_load(&ws[(size_t)j  * JS + (size_t)k * NBQ + bq],
                                     __ATOMIC_RELAXED, __HIP_MEMORY_SCOPE_AGENT);
            den += __hip_atomic_load(&ws[(size_t)DY * JS + (size_t)k * NBQ + bq],
                                     __ATOMIC_RELAXED, __HIP_MEMORY_SCOPE_AGENT);
        }
        out[(size_t)bq * (DY + 1) + j] = (j == DY) ? den : s / (den + 1e-8f);
    }
}

// ---- standalone accum (fallback when cooperative launch unavailable) ----
__global__ __launch_bounds__(256, 4) void setconv_accum_mfma(
    const float* __restrict__ xq, const float* __restrict__ xc,
    const float* __restrict__ yc, const float* __restrict__ lls,
    float* __restrict__ ws)
{
    __shared__ float4 sxp[NPAIR];
    __shared__ float2 shp[NPAIR];
    __shared__ __attribute__((aligned(16)))
        unsigned short yfrag[CCHUNK / 8][16][8];
    accum_phase(xq, xc, yc, lls, ws, sxp, shp, yfrag);
}

// Reduce over GSPLIT=8 + normalize (proven). Block: 64 queries.
__global__ __launch_bounds__(256) void setconv_reduce(
    const float* __restrict__ ws, float* __restrict__ out)
{
    __shared__ float part[4][64][DY + 1];
    const int tid  = threadIdx.x;
    const int qi   = tid & 63;
    const int sg   = tid >> 6;
    const int base = blockIdx.x * 64;
    const int bq   = base + qi;

#pragma unroll
    for (int j = 0; j < DY + 1; ++j) {
        float s = 0.f;
#pragma unroll
        for (int k = 0; k < GSPLIT / 4; ++k) {
            const int split = sg * (GSPLIT / 4) + k;
            s += ws[(size_t)j * JS + (size_t)split * NBQ + bq];  // coalesced
        }
        part[sg][qi][j] = s;
    }
    __syncthreads();

    for (int it = tid; it < 64 * (DY + 1); it += 256) {
        const int q2 = it / (DY + 1);
        const int j  = it - q2 * (DY + 1);
        const float den = part[0][q2][DY] + part[1][q2][DY] +
                          part[2][q2][DY] + part[3][q2][DY];
        float v;
        if (j == DY) {
            v = den;
        } else {
            const float s = part[0][q2][j] + part[1][q2][j] +
                            part[2][q2][j] + part[3][q2][j];
            v = s / (den + 1e-8f);
        }
        out[(size_t)base * (DY + 1) + it] = v;    // coalesced
    }
}

// ---------------- fallback path (round-1, known-good): atomics ----------------
#define FSPLIT 8
#define FCCH (NC / FSPLIT)

__global__ __launch_bounds__(256) void setconv_zero(float4* __restrict__ out) {
    out[blockIdx.x * 256 + threadIdx.x] = make_float4(0.f, 0.f, 0.f, 0.f);
}

__global__ __launch_bounds__(256) void setconv_accum_atomic(
    const float* __restrict__ xq, const float* __restrict__ xc,
    const float* __restrict__ yc, const float* __restrict__ lls,
    float* __restrict__ out)
{
    const int bid   = blockIdx.x;
    const int split = bid & (FSPLIT - 1);
    const int qblk  = (bid / FSPLIT) & (NQ / 256 - 1);
    const int b     = bid / (FSPLIT * (NQ / 256));
    const int q     = qblk * 256 + threadIdx.x;

    const float L    = lls[0];
    const float negk = -0.72134752044448f * EXP2F(L * -2.8853900817779268f);

    const float2 qv = ((const float2*)xq)[b * NQ + q];
    const float qx0 = qv.x, qy0 = qv.y;

    float acc[DY], den = 0.f;
#pragma unroll
    for (int j = 0; j < DY; ++j) acc[j] = 0.f;

    const float2* __restrict__ xcp = ((const float2*)xc) + (size_t)b * NC;
    const float4* __restrict__ ycp = ((const float4*)yc) + (size_t)b * NC * 2;

    const int c0 = split * FCCH;
#pragma unroll 4
    for (int c = c0; c < c0 + FCCH; ++c) {
        const float2 cv = xcp[c];
        const float4 y0 = ycp[2 * c + 0];
        const float4 y1 = ycp[2 * c + 1];
        const float dx = qx0 - cv.x;
        const float dy = qy0 - cv.y;
        const float d2 = fmaf(dy, dy, dx * dx);
        const float w  = EXP2F(d2 * negk);
        den += w;
        acc[0] = fmaf(w, y0.x, acc[0]);
        acc[1] = fmaf(w, y0.y, acc[1]);
        acc[2] = fmaf(w, y0.z, acc[2]);
        acc[3] = fmaf(w, y0.w, acc[3]);
        acc[4] = fmaf(w, y1.x, acc[4]);
        acc[5] = fmaf(w, y1.y, acc[5]);
        acc[6] = fmaf(w, y1.z, acc[6]);
        acc[7] = fmaf(w, y1.w, acc[7]);
    }

    float* o = out + (size_t)(b * NQ + q) * (DY + 1);
#pragma unroll
    for (int j = 0; j < DY; ++j) atomicAdd(o + j, acc[j]);
    atomicAdd(o + DY, den);
}

__global__ __launch_bounds__(256) void setconv_norm(float* __restrict__ out) {
    const int q = blockIdx.x * 256 + threadIdx.x;
    float* o = out + (size_t)q * (DY + 1);
    const float inv = 1.0f / (o[DY] + 1e-8f);
#pragma unroll
    for (int j = 0; j < DY; ++j) o[j] *= inv;
}

extern "C" void kernel_launch(void* const* d_in, const int* in_sizes, int n_in,
                              void* d_out, int out_size, void* d_ws, size_t ws_size,
                              hipStream_t stream) {
    const float* xq  = (const float*)d_in[0];  // (4,4096,2)
    const float* xc  = (const float*)d_in[1];  // (4,4096,2)
    const float* yc  = (const float*)d_in[2];  // (4,4096,8)
    const float* lls = (const float*)d_in[3];  // scalar
    float* out = (float*)d_out;                // (4,4096,9)

    if (ws_size >= WS_FLOATS * sizeof(float)) {
        float* ws = (float*)d_ws;
        void* args[] = {(void*)&xq, (void*)&xc, (void*)&yc,
                        (void*)&lls, (void*)&ws, (void*)&out};
        hipError_t e = hipLaunchCooperativeKernel(
            (const void*)setconv_fused, dim3(NBLK), dim3(256), args, 0, stream);
        if (e != hipSuccess) {
            (void)hipGetLastError();           // clear sticky error
            setconv_accum_mfma<<<NBLK, 256, 0, stream>>>(xq, xc, yc, lls, ws);
            setconv_reduce<<<NBQ / 64, 256, 0, stream>>>(ws, out);
        }
    } else {
        setconv_zero<<<(NBQ * (DY + 1)) / 1024, 256, 0, stream>>>((float4*)out);
        setconv_accum_atomic<<<BB * (NQ / 256) * FSPLIT, 256, 0, stream>>>(xq, xc, yc, lls, out);
        setconv_norm<<<NBQ / 256, 256, 0, stream>>>(out);
    }
}

// Round 8
// 74.213 us; speedup vs baseline: 2.8078x; 2.8078x over previous
//
#include <hip/hip_runtime.h>

// SetConv RBF: B=4, NQ=4096, NC=4096, DC=2, DY=8, fp32.
// out[b,q,0:8] = sum_c w(q,c)*y[c] / (den+1e-8); out[b,q,8] = den = sum_c w(q,c)
//
// MEASURED LAWS (prior session R1-R10, this session R11-R17):
//  - dur_us = ~41us harness d_ws poison fill (268MB, 82% HBM, ws-usage-indep)
//    + ~10us fixed/gaps (3 dispatches ~3us/gap) + kernel time.
//  - Dense MFMA path: accum ~20us + reduce ~2.5us => 73.6 total (67M pairs).
//  - Binning FALSIFIED (R11-R13, best 118): pipeline tax + latency-bound sparse
//    loops >= pair savings. Global-load-per-trip loops latency-bound at any occ.
//  - ACCUM LEDGER: ~20us dur; ~8us VALU-busy (R17 fused counters); invariant to
//    VALU diet (R10), DS diet (R14), partition (R14), occupancy 4->6 (R15);
//    VALU marginal slope=1 (R16: +6.8 pred/+7.3 meas); NOT TRANS (R16), NOT
//    memory (R17: 5.7MB fetch, 1% HBM), NOT MFMA (R17: 0.6% util). Remaining
//    ~12us stall unattributable without accum SQ counters (fills hog top-5).
//  - R17 COOP FALSIFIED: grid.sync stalls ~115us + ~20us/iter launch overhead
//    (non-capturable). Single-kernel fusion otherwise blocked: ws is poisoned
//    each iter => last-block counters need an init launch (nets ~0).
// R18: revert to measured-best R15 geometry (QPB 64, NT 4, lb(256,6), 2048
// blocks) + widen reduce to 512 blocks x 32 q (1 split/thread-group) to shave
// its latency-bound 2.5us. Predicted: 73.2-73.6, absmax 0.25, top-5 = fills.
// If confirmed => structural ceiling: 41 fill + ~10 fixed + ~20 accum + ~2 red.

#define BB 4
#define NQ 4096
#define NC 4096
#define DY 8
#define NBQ (BB * NQ)           // 16384 queries total

#if __has_builtin(__builtin_amdgcn_exp2f)
#define EXP2F(x) __builtin_amdgcn_exp2f(x)
#else
#define EXP2F(x) exp2f(x)
#endif

typedef short bf16x8 __attribute__((ext_vector_type(8)));
typedef float f32x4  __attribute__((ext_vector_type(4)));
typedef float f32x2  __attribute__((ext_vector_type(2)));

__device__ __forceinline__ short f2bf(float v) {
    return (short)(__builtin_bit_cast(unsigned, v) >> 16);   // truncate
}
__device__ __forceinline__ unsigned fbits(float v) {
    return __builtin_bit_cast(unsigned, v);
}
// pack hi16(w0) -> low half, hi16(w1) -> high half (bf16 pair dword)
__device__ __forceinline__ unsigned bfpair(float w0, float w1) {
#if __has_builtin(__builtin_amdgcn_perm)
    return __builtin_amdgcn_perm(fbits(w1), fbits(w0), 0x07060302u);
#else
    return (fbits(w1) & 0xFFFF0000u) | (fbits(w0) >> 16);
#endif
}

// ---------------- fast path (MFMA, k-major waves; R15 geometry) ----------------
#define GSPLIT 8                     // global context split
#define CCHUNK (NC / GSPLIT)         // 512 contexts per block
#define NPAIR (CCHUNK / 2)           // 256 context pairs
#define KSTEPS (CCHUNK / 32)         // 16 mfma k-steps
#define QPB 64                       // queries per block: 4 tiles x 16
#define NT 4                         // q-tiles per block
#define KPW (KSTEPS / 4)             // 4 k-steps per wave
#define QB (NBQ / QPB)               // 256 query-blocks
#define JS ((size_t)GSPLIT * NBQ)                     // 131072
#define WS_FLOATS ((size_t)(DY + 1) * GSPLIT * NBQ)   // 1.18M floats = 4.7 MB

// grid = QB*GSPLIT = 2048 blocks of 256; LDS 22KB, VGPR capped via lb(256,6).
__global__ __launch_bounds__(256, 6) void setconv_accum_mfma(
    const float* __restrict__ xq, const float* __restrict__ xc,
    const float* __restrict__ yc, const float* __restrict__ lls,
    float* __restrict__ ws)
{
    __shared__ float4 sxp[NPAIR];                        // (cx0,cx1,cy0,cy1) 4 KB
    __shared__ float2 shp[NPAIR];                        // (hc0,hc1)         2 KB
    __shared__ __attribute__((aligned(16)))
        unsigned short yfrag[CCHUNK / 8][16][8];         // B-frag layout    16 KB

    const int bid  = blockIdx.x;              // 0..2047
    const int gs   = bid & (GSPLIT - 1);
    const int qb   = bid >> 3;                // 0..255
    const int b    = qb >> 6;                 // 64 q-blocks per batch
    const int tid  = threadIdx.x;
    const int lane = tid & 63;
    const int wv   = tid >> 6;
    const int m    = lane & 15;               // A row / D col index
    const int quad = lane >> 4;

    const float L    = lls[0];
    const float negk = -0.72134752044448f * EXP2F(L * -2.8853900817779268f);

    // ---- stage ctx pairs: tid == pair index (proven) ----
    {
        const float4* xcp = (const float4*)(((const float2*)xc) + (size_t)b * NC + gs * CCHUNK);
        const float4 v = xcp[tid];            // (cx0,cy0,cx1,cy1)
        sxp[tid] = make_float4(v.x, v.z, v.y, v.w);
        shp[tid] = make_float2(negk * fmaf(v.x, v.x, v.y * v.y),
                               negk * fmaf(v.z, v.z, v.w * v.w));
    }
    // ---- stage Ytilde in B-fragment layout: yfrag[g][n][j] = Y[8g+j][n] ----
    {
        const float4* yp = (const float4*)(yc + ((size_t)b * NC + gs * CCHUNK) * DY);
#pragma unroll
        for (int i = 0; i < 2; ++i) {
            const int c = tid + 256 * i;
            const float4 A  = yp[2 * c + 0];
            const float4 Bv = yp[2 * c + 1];
            const int g = c >> 3, j = c & 7;
            unsigned short* dst = &yfrag[g][0][j];
            dst[0 * 8] = (unsigned short)f2bf(A.x);
            dst[1 * 8] = (unsigned short)f2bf(A.y);
            dst[2 * 8] = (unsigned short)f2bf(A.z);
            dst[3 * 8] = (unsigned short)f2bf(A.w);
            dst[4 * 8] = (unsigned short)f2bf(Bv.x);
            dst[5 * 8] = (unsigned short)f2bf(Bv.y);
            dst[6 * 8] = (unsigned short)f2bf(Bv.z);
            dst[7 * 8] = (unsigned short)f2bf(Bv.w);
        }
        // cols 8..15: col 8 = 1.0 (density), 9..15 = 0
        unsigned* yf32 = (unsigned*)yfrag;    // u32 idx = g*64 + n*4 + (j>>1)
#pragma unroll
        for (int i = 0; i < 8; ++i) {         // (CCHUNK/8)*32/256 = 8
            const int v = tid + 256 * i;
            const int g = v >> 5, r = v & 31; // r = (n-8)*4 + jpair
            yf32[g * 64 + 32 + r] = (r < 4) ? 0x3F803F80u : 0u;
        }
    }

    // ---- per-query coefficients for the 4 tiles (lane m = query row) ----
    float A0s[NT], A1s[NT], A2s[NT];
#pragma unroll
    for (int t = 0; t < NT; ++t) {
        const int q = qb * QPB + t * 16 + m;
        const float2 qv = ((const float2*)xq)[q];
        A0s[t] = negk * fmaf(qv.x, qv.x, qv.y * qv.y);
        A1s[t] = -2.f * negk * qv.x;
        A2s[t] = -2.f * negk * qv.y;
    }

    f32x4 acc[NT];
#pragma unroll
    for (int t = 0; t < NT; ++t) acc[t] = (f32x4){0.f, 0.f, 0.f, 0.f};

    __syncthreads();

    // ---- hot loop: wave wv owns k-steps 4wv..4wv+3, all 4 q-tiles (R14/R15) ----
    for (int ks = 0; ks < KPW; ++ks) {
        const int s = wv * KPW + ks;
        const bf16x8 bfrag = *(const bf16x8*)&yfrag[s * 4 + quad][m][0];
        float4 xp[4]; float2 hp[4];
#pragma unroll
        for (int jp = 0; jp < 4; ++jp) {
            const int P = s * 16 + quad * 4 + jp;
            xp[jp] = sxp[P];
            hp[jp] = shp[P];
        }
#pragma unroll
        for (int t = 0; t < NT; ++t) {
            const f32x2 a0 = {A0s[t], A0s[t]};
            const f32x2 a1 = {A1s[t], A1s[t]};
            const f32x2 a2 = {A2s[t], A2s[t]};
            unsigned au[4];
#pragma unroll
            for (int jp = 0; jp < 4; ++jp) {
                const f32x2 cx2 = {xp[jp].x, xp[jp].y};
                const f32x2 cy2 = {xp[jp].z, xp[jp].w};
                const f32x2 hc2 = {hp[jp].x, hp[jp].y};
                f32x2 tt = __builtin_elementwise_fma(cx2, a1, hc2 + a0);
                tt = __builtin_elementwise_fma(cy2, a2, tt);
                au[jp] = bfpair(EXP2F(tt.x), EXP2F(tt.y));
            }
            const bf16x8 af = __builtin_bit_cast(bf16x8, *(uint4*)au);
            acc[t] = __builtin_amdgcn_mfma_f32_16x16x32_bf16(af, bfrag, acc[t], 0, 0, 0);
        }
    }

    // ---- cross-wave reduce of k-split partials, write ws (1 tile/round) ----
    // rb layout [w][lane]: lane stride 16B -> conflict-free b128. 4KB in yfrag.
    __syncthreads();                          // all yfrag/sxp reads done
    float4* rb = (float4*)&yfrag[0][0][0];
    for (int h = 0; h < NT; ++h) {
        rb[wv * 64 + lane] = make_float4(acc[h][0], acc[h][1], acc[h][2], acc[h][3]);
        __syncthreads();
        if (wv == h && m <= 8) {
            float4 v = rb[0 * 64 + lane];
#pragma unroll
            for (int w = 1; w < 4; ++w) {
                const float4 z = rb[w * 64 + lane];
                v.x += z.x; v.y += z.y; v.z += z.z; v.w += z.w;
            }
            *(float4*)&ws[(size_t)m * JS + (size_t)gs * NBQ +
                          (size_t)qb * QPB + h * 16 + quad * 4] = v;
        }
        __syncthreads();
    }
}

// Reduce over GSPLIT=8 + normalize. R18: 512 blocks x 32 queries, 8 groups of
// 1 split each (doubled parallelism for the latency-bound phase).
#define RQB 32
__global__ __launch_bounds__(256) void setconv_reduce(
    const float* __restrict__ ws, float* __restrict__ out)
{
    __shared__ float part[GSPLIT][RQB][DY + 1];   // 9 KB
    const int tid  = threadIdx.x;
    const int qi   = tid & (RQB - 1);
    const int sg   = tid >> 5;                    // 0..7 = split
    const int base = blockIdx.x * RQB;
    const int bq   = base + qi;

#pragma unroll
    for (int j = 0; j < DY + 1; ++j)               // coalesced across qi
        part[sg][qi][j] = ws[(size_t)j * JS + (size_t)sg * NBQ + bq];
    __syncthreads();

    for (int it = tid; it < RQB * (DY + 1); it += 256) {
        const int q2 = it / (DY + 1);
        const int j  = it - q2 * (DY + 1);
        float den = 0.f, s = 0.f;
#pragma unroll
        for (int k = 0; k < GSPLIT; ++k) {
            den += part[k][q2][DY];
            s   += part[k][q2][j];
        }
        out[(size_t)base * (DY + 1) + it] = (j == DY) ? den : s / (den + 1e-8f);
    }
}

// ---------------- fallback path (round-1, known-good): atomics ----------------
#define FSPLIT 8
#define FCCH (NC / FSPLIT)

__global__ __launch_bounds__(256) void setconv_zero(float4* __restrict__ out) {
    out[blockIdx.x * 256 + threadIdx.x] = make_float4(0.f, 0.f, 0.f, 0.f);
}

__global__ __launch_bounds__(256) void setconv_accum_atomic(
    const float* __restrict__ xq, const float* __restrict__ xc,
    const float* __restrict__ yc, const float* __restrict__ lls,
    float* __restrict__ out)
{
    const int bid   = blockIdx.x;
    const int split = bid & (FSPLIT - 1);
    const int qblk  = (bid / FSPLIT) & (NQ / 256 - 1);
    const int b     = bid / (FSPLIT * (NQ / 256));
    const int q     = qblk * 256 + threadIdx.x;

    const float L    = lls[0];
    const float negk = -0.72134752044448f * EXP2F(L * -2.8853900817779268f);

    const float2 qv = ((const float2*)xq)[b * NQ + q];
    const float qx0 = qv.x, qy0 = qv.y;

    float acc[DY], den = 0.f;
#pragma unroll
    for (int j = 0; j < DY; ++j) acc[j] = 0.f;

    const float2* __restrict__ xcp = ((const float2*)xc) + (size_t)b * NC;
    const float4* __restrict__ ycp = ((const float4*)yc) + (size_t)b * NC * 2;

    const int c0 = split * FCCH;
#pragma unroll 4
    for (int c = c0; c < c0 + FCCH; ++c) {
        const float2 cv = xcp[c];
        const float4 y0 = ycp[2 * c + 0];
        const float4 y1 = ycp[2 * c + 1];
        const float dx = qx0 - cv.x;
        const float dy = qy0 - cv.y;
        const float d2 = fmaf(dy, dy, dx * dx);
        const float w  = EXP2F(d2 * negk);
        den += w;
        acc[0] = fmaf(w, y0.x, acc[0]);
        acc[1] = fmaf(w, y0.y, acc[1]);
        acc[2] = fmaf(w, y0.z, acc[2]);
        acc[3] = fmaf(w, y0.w, acc[3]);
        acc[4] = fmaf(w, y1.x, acc[4]);
        acc[5] = fmaf(w, y1.y, acc[5]);
        acc[6] = fmaf(w, y1.z, acc[6]);
        acc[7] = fmaf(w, y1.w, acc[7]);
    }

    float* o = out + (size_t)(b * NQ + q) * (DY + 1);
#pragma unroll
    for (int j = 0; j < DY; ++j) atomicAdd(o + j, acc[j]);
    atomicAdd(o + DY, den);
}

__global__ __launch_bounds__(256) void setconv_norm(float* __restrict__ out) {
    const int q = blockIdx.x * 256 + threadIdx.x;
    float* o = out + (size_t)q * (DY + 1);
    const float inv = 1.0f / (o[DY] + 1e-8f);
#pragma unroll
    for (int j = 0; j < DY; ++j) o[j] *= inv;
}

extern "C" void kernel_launch(void* const* d_in, const int* in_sizes, int n_in,
                              void* d_out, int out_size, void* d_ws, size_t ws_size,
                              hipStream_t stream) {
    const float* xq  = (const float*)d_in[0];  // (4,4096,2)
    const float* xc  = (const float*)d_in[1];  // (4,4096,2)
    const float* yc  = (const float*)d_in[2];  // (4,4096,8)
    const float* lls = (const float*)d_in[3];  // scalar
    float* out = (float*)d_out;                // (4,4096,9)

    if (ws_size >= WS_FLOATS * sizeof(float)) {
        float* ws = (float*)d_ws;
        setconv_accum_mfma<<<QB * GSPLIT, 256, 0, stream>>>(xq, xc, yc, lls, ws);
        setconv_reduce<<<NBQ / RQB, 256, 0, stream>>>(ws, out);
    } else {
        setconv_zero<<<(NBQ * (DY + 1)) / 1024, 256, 0, stream>>>((float4*)out);
        setconv_accum_atomic<<<BB * (NQ / 256) * FSPLIT, 256, 0, stream>>>(xq, xc, yc, lls, out);
        setconv_norm<<<NBQ / 256, 256, 0, stream>>>(out);
    }
}